// Round 1
// 1879.107 us; speedup vs baseline: 1.0174x; 1.0174x over previous
//
#include <hip/hip_runtime.h>

#define DI __device__ __forceinline__

typedef __bf16 bf16;
typedef bf16 bf16x2 __attribute__((ext_vector_type(2)));
typedef bf16 bf16x4 __attribute__((ext_vector_type(4)));
typedef bf16 bf16x8 __attribute__((ext_vector_type(8)));
typedef float f32x4 __attribute__((ext_vector_type(4)));

static constexpr int B  = 4;
static constexpr int S  = 2048;
static constexpr int H  = 2048;
static constexpr int NH = 16;
static constexpr int HD = 128;
static constexpr int KE = 8;
static constexpr int M  = B * S;   // 8192

DI bf16 f2bf(float x) {
  union { float f; unsigned u; } v; v.f = x;
  unsigned rr = (v.u + 0x7FFFu + ((v.u >> 16) & 1u)) >> 16;
  union { unsigned short s; bf16 b; } o; o.s = (unsigned short)rr;
  return o.b;
}

DI void async_copy16(void* lds, const void* g) {
  __builtin_amdgcn_global_load_lds(
      (const __attribute__((address_space(1))) unsigned int*)g,
      (__attribute__((address_space(3))) unsigned int*)lds, 16, 0, 0);
}

// ---------------- elementwise fp32 -> bf16 ----------------
__global__ __launch_bounds__(256) void k_conv_bf16(const float* __restrict__ x,
                                                   bf16* __restrict__ y, int n4) {
  int i = blockIdx.x * 256 + threadIdx.x;
  if (i >= n4) return;
  float4 v = ((const float4*)x)[i];
  bf16x4 o = { f2bf(v.x), f2bf(v.y), f2bf(v.z), f2bf(v.w) };
  ((bf16x4*)y)[i] = o;
}

// ---------------- W [H,H] fp32 -> Wt [H,H] bf16 (transposed) ----------------
__global__ __launch_bounds__(256) void k_transpose_w(const float* __restrict__ W,
                                                     bf16* __restrict__ Wt) {
  __shared__ float tile[32][33];
  int tx = threadIdx.x & 31, ty = threadIdx.x >> 5;  // ty 0..7
  int n0 = blockIdx.x << 5, k0 = blockIdx.y << 5;
  #pragma unroll
  for (int i = 0; i < 32; i += 8)
    tile[ty + i][tx] = W[(long)(k0 + ty + i) * H + n0 + tx];
  __syncthreads();
  #pragma unroll
  for (int i = 0; i < 32; i += 8)
    Wt[(long)(n0 + ty + i) * H + k0 + tx] = f2bf(tile[tx][ty + i]);
}

// ---------------- gate: softmax over first 2 of (hs @ W_gate + b) ----------------
__global__ __launch_bounds__(256) void k_gate(const float* __restrict__ hs,
                                              const float* __restrict__ Wg,
                                              const float* __restrict__ bg,
                                              float* __restrict__ g) {
  int wave = threadIdx.x >> 6, lane = threadIdx.x & 63;
  int m = blockIdx.x * 4 + wave;
  const float* row = hs + (long)m * H;
  float a0 = 0.f, a1 = 0.f;
  #pragma unroll
  for (int i = 0; i < H / 256; ++i) {
    int h = i * 256 + lane * 4;
    float4 x = *(const float4*)(row + h);
    a0 += x.x * Wg[h*3]   + x.y * Wg[(h+1)*3]   + x.z * Wg[(h+2)*3]   + x.w * Wg[(h+3)*3];
    a1 += x.x * Wg[h*3+1] + x.y * Wg[(h+1)*3+1] + x.z * Wg[(h+2)*3+1] + x.w * Wg[(h+3)*3+1];
  }
  #pragma unroll
  for (int d = 1; d < 64; d <<= 1) { a0 += __shfl_xor(a0, d); a1 += __shfl_xor(a1, d); }
  if (lane == 0) {
    float l0 = a0 + bg[0], l1 = a1 + bg[1];
    float g0 = 1.f / (1.f + expf(l1 - l0));
    g[m*2] = g0; g[m*2+1] = 1.f - g0;
  }
}

// ---------------- bf16 MFMA GEMM: C[M,H] = A[M,H] @ Bt[H,H]^T ----------------
// MODE 0: bf16 out, layout [B,NH,S,HD]      (q, k)
// MODE 3: bf16 out, layout [B,NH,HD,S]      (v transposed)
// MODE 1: fp32 out, row-major [M,H]         (attn_output)
// MODE 2: fp32 out = g0*attn + g1*acc       (final combine)
template<int MODE>
__global__ __launch_bounds__(256, 2)
void k_gemm(const bf16* __restrict__ A, const bf16* __restrict__ Bt,
            void* C, const float* attn, const float* gate) {
  constexpr int Kd = H;
  __shared__ __align__(16) bf16 As[128 * 32];
  __shared__ __align__(16) bf16 Bs[128 * 32];

  const int tid = threadIdx.x;
  const int wave = tid >> 6, lane = tid & 63;
  const int q = lane >> 4, r = lane & 15;
  const int m0 = blockIdx.y << 7, n0 = blockIdx.x << 7;
  const int wm = (wave >> 1) << 6, wn = (wave & 1) << 6;
  const int srow = lane >> 2, skof = (lane & 3) << 3;

  f32x4 acc[4][4] = {};

  const bf16* Abase = A + (long)(m0 + (wave << 5) + srow) * Kd + skof;
  const bf16* Bbase = Bt + (long)(n0 + (wave << 5) + srow) * Kd + skof;

  for (int kt = 0; kt < Kd; kt += 32) {
    __syncthreads();
    async_copy16((char*)As + (wave * 2) * 1024,     Abase + kt);
    async_copy16((char*)As + (wave * 2 + 1) * 1024, Abase + 16 * Kd + kt);
    async_copy16((char*)Bs + (wave * 2) * 1024,     Bbase + kt);
    async_copy16((char*)Bs + (wave * 2 + 1) * 1024, Bbase + 16 * Kd + kt);
    __syncthreads();

    bf16x8 af[4], bfr[4];
    #pragma unroll
    for (int i = 0; i < 4; ++i)
      af[i] = *(const bf16x8*)&As[(wm + i * 16 + r) * 32 + q * 8];
    #pragma unroll
    for (int j = 0; j < 4; ++j)
      bfr[j] = *(const bf16x8*)&Bs[(wn + j * 16 + r) * 32 + q * 8];
    #pragma unroll
    for (int i = 0; i < 4; ++i)
      #pragma unroll
      for (int j = 0; j < 4; ++j)
        acc[i][j] = __builtin_amdgcn_mfma_f32_16x16x32_bf16(af[i], bfr[j], acc[i][j], 0, 0, 0);
  }

  const int gm = m0 + wm;  // + i*16 + q*4 + rr
  const int gn = n0 + wn;  // + j*16 + r

  if constexpr (MODE == 0) {
    bf16* out = (bf16*)C;
    #pragma unroll
    for (int i = 0; i < 4; ++i)
      #pragma unroll
      for (int j = 0; j < 4; ++j) {
        int n = gn + j * 16 + r;
        int nh = n >> 7, hd = n & 127;
        #pragma unroll
        for (int rr = 0; rr < 4; ++rr) {
          int m = gm + i * 16 + (q << 2) + rr;
          int b = m >> 11, s = m & 2047;
          out[(((long)(b * NH + nh) * S + s) << 7) + hd] = f2bf(acc[i][j][rr]);
        }
      }
  } else if constexpr (MODE == 3) {
    bf16* out = (bf16*)C;
    #pragma unroll
    for (int i = 0; i < 4; ++i)
      #pragma unroll
      for (int j = 0; j < 4; ++j) {
        int n = gn + j * 16 + r;
        int nh = n >> 7, hd = n & 127;
        int m = gm + i * 16 + (q << 2);
        int b = m >> 11, s = m & 2047;
        bf16x4 v = { f2bf(acc[i][j][0]), f2bf(acc[i][j][1]),
                     f2bf(acc[i][j][2]), f2bf(acc[i][j][3]) };
        *(bf16x4*)&out[(((long)(b * NH + nh) * HD + hd) << 11) + s] = v;
      }
  } else if constexpr (MODE == 1) {
    float* out = (float*)C;
    #pragma unroll
    for (int i = 0; i < 4; ++i)
      #pragma unroll
      for (int j = 0; j < 4; ++j) {
        int n = gn + j * 16 + r;
        #pragma unroll
        for (int rr = 0; rr < 4; ++rr) {
          int m = gm + i * 16 + (q << 2) + rr;
          out[(long)m * H + n] = acc[i][j][rr];
        }
      }
  } else {  // MODE 2
    float* out = (float*)C;
    #pragma unroll
    for (int i = 0; i < 4; ++i)
      #pragma unroll
      for (int rr = 0; rr < 4; ++rr) {
        int m = gm + i * 16 + (q << 2) + rr;
        float g0 = gate[m * 2], g1 = gate[m * 2 + 1];
        long rowoff = (long)m * H;
        #pragma unroll
        for (int j = 0; j < 4; ++j) {
          int n = gn + j * 16 + r;
          out[rowoff + n] = g0 * attn[rowoff + n] + g1 * acc[i][j][rr];
        }
      }
  }
}

// ---------------- causal flash attention ----------------
// Q,K: [B,NH,S,HD] bf16.  Vt: [B,NH,HD,S] bf16.  ctx out: [B,S,NH,HD] bf16.
// Double-buffered K/V tiles (T3 2-phase): one barrier per K-tile, the stage for
// tile kt+1 is issued BEFORE computing on tile kt so the vmcnt(0) drain at the
// trailing __syncthreads() lands after a full compute phase.
__global__ __launch_bounds__(256, 2)
void k_flash(const bf16* __restrict__ Qg, const bf16* __restrict__ Kg,
             const bf16* __restrict__ Vtg, bf16* __restrict__ ctx) {
  __shared__ __align__(16) bf16 Ks[2][64 * 128];
  __shared__ __align__(16) bf16 Vs[2][128 * 64];
  __shared__ __align__(16) bf16 Ps[4][16 * 64];

  const int tid = threadIdx.x;
  const int wave = tid >> 6, lane = tid & 63;
  const int q = lane >> 4, r = lane & 15;
  const int bh = blockIdx.y;
  const int qt = gridDim.x - 1 - blockIdx.x;   // LPT: longest q-tiles dispatch first
  const int qrow0 = (qt << 6) + (wave << 4);

  const bf16* Qb = Qg + (long)bh * S * HD;
  const bf16* Kb = Kg + (long)bh * S * HD;
  const bf16* Vb = Vtg + (long)bh * HD * S;

  bf16x8 qf[4];
  #pragma unroll
  for (int c = 0; c < 4; ++c)
    qf[c] = *(const bf16x8*)&Qb[(qrow0 + r) * HD + (c << 5) + (q << 3)];

  f32x4 o[8] = {};
  f32x4 m_run = { -3.0e38f, -3.0e38f, -3.0e38f, -3.0e38f };
  f32x4 l_run = {};

  constexpr float kscale = 0.08838834764831845f * 1.4426950408889634f;

  // stage tile kt into buffer buf (XOR-swizzled 16B chunks, linear LDS dest)
  auto stage = [&](int kt, int buf) {
    #pragma unroll
    for (int p = 0; p < 4; ++p) {
      const int seg = (wave << 2) + p;
      {
        const int key = (seg << 2) + (lane >> 4);
        const int clog = (lane & 15) ^ (key & 15);
        const char* src = (const char*)(Kb + ((long)(kt << 6) + key) * HD) + (clog << 4);
        async_copy16((char*)&Ks[buf][0] + (seg << 10), src);
      }
      {
        const int hd = (seg << 3) + (lane >> 3);
        const int clog = (lane & 7) ^ (hd & 7);
        const char* src = (const char*)(Vb + (long)hd * S + (kt << 6)) + (clog << 4);
        async_copy16((char*)&Vs[buf][0] + (seg << 10), src);
      }
    }
  };

  stage(0, 0);
  __syncthreads();   // drain prologue loads; buf0 ready

  int cur = 0;
  for (int kt = 0; kt <= qt; ++kt) {
    if (kt < qt) stage(kt + 1, cur ^ 1);   // prefetch next tile (no wait)

    const bf16* Kc = &Ks[cur][0];
    const bf16* Vc = &Vs[cur][0];

    // S = Q @ K^T  (C-layout: row = q*4+rr, col = j*16+r)
    f32x4 sv[4];
    __builtin_amdgcn_s_setprio(1);
    #pragma unroll
    for (int j = 0; j < 4; ++j) {
      f32x4 s = {};
      #pragma unroll
      for (int c = 0; c < 4; ++c) {
        const bf16x8 kf = *(const bf16x8*)&Kc[((j << 4) + r) * 128 + ((((c << 2) + q) ^ r) << 3)];
        s = __builtin_amdgcn_mfma_f32_16x16x32_bf16(qf[c], kf, s, 0, 0, 0);
      }
      sv[j] = s * kscale;
    }
    __builtin_amdgcn_s_setprio(0);

    if (kt == qt) {
      #pragma unroll
      for (int j = 0; j < 4; ++j) {
        const int col = (kt << 6) + (j << 4) + r;
        #pragma unroll
        for (int rr = 0; rr < 4; ++rr) {
          const int row = qrow0 + (q << 2) + rr;
          if (col > row) sv[j][rr] = -3.0e38f;
        }
      }
    }

    f32x4 mx = sv[0];
    #pragma unroll
    for (int j = 1; j < 4; ++j)
      #pragma unroll
      for (int t = 0; t < 4; ++t) mx[t] = fmaxf(mx[t], sv[j][t]);
    #pragma unroll
    for (int t = 0; t < 4; ++t) {
      float v = mx[t];
      v = fmaxf(v, __shfl_xor(v, 1));
      v = fmaxf(v, __shfl_xor(v, 2));
      v = fmaxf(v, __shfl_xor(v, 4));
      v = fmaxf(v, __shfl_xor(v, 8));
      mx[t] = v;
    }

    f32x4 m_new, alpha;
    #pragma unroll
    for (int t = 0; t < 4; ++t) {
      m_new[t] = fmaxf(m_run[t], mx[t]);
      alpha[t] = exp2f(m_run[t] - m_new[t]);
    }

    f32x4 ps = {};
    #pragma unroll
    for (int j = 0; j < 4; ++j) {
      f32x4 p;
      #pragma unroll
      for (int t = 0; t < 4; ++t) p[t] = exp2f(sv[j][t] - m_new[t]);
      ps += p;
      #pragma unroll
      for (int rr = 0; rr < 4; ++rr) {
        const int row = (q << 2) + rr;
        const int cw = ((j << 1) + (r >> 3)) ^ (row & 7);
        Ps[wave][(row << 6) + (cw << 3) + (r & 7)] = f2bf(p[rr]);
      }
    }

    #pragma unroll
    for (int t = 0; t < 4; ++t) {
      float v = ps[t];
      v += __shfl_xor(v, 1);
      v += __shfl_xor(v, 2);
      v += __shfl_xor(v, 4);
      v += __shfl_xor(v, 8);
      l_run[t] = l_run[t] * alpha[t] + v;
      m_run[t] = m_new[t];
    }

    #pragma unroll
    for (int j2 = 0; j2 < 8; ++j2) o[j2] *= alpha;

    // O += P @ V   (P read back in A-layout; same-wave LDS ops are in order)
    bf16x8 pa[2];
    #pragma unroll
    for (int c = 0; c < 2; ++c)
      pa[c] = *(const bf16x8*)&Ps[wave][(r << 6) + ((((c << 2) + q) ^ (r & 7)) << 3)];
    __builtin_amdgcn_s_setprio(1);
    #pragma unroll
    for (int j2 = 0; j2 < 8; ++j2) {
      #pragma unroll
      for (int c = 0; c < 2; ++c) {
        const bf16x8 vf = *(const bf16x8*)&Vc[((j2 << 4) + r) * 64 + ((((c << 2) + q) ^ (r & 7)) << 3)];
        o[j2] = __builtin_amdgcn_mfma_f32_16x16x32_bf16(pa[c], vf, o[j2], 0, 0, 0);
      }
    }
    __builtin_amdgcn_s_setprio(0);

    __syncthreads();   // drains prefetch vmcnt + syncs; buf cur^1 ready, buf cur free
    cur ^= 1;
  }

  f32x4 inv;
  #pragma unroll
  for (int t = 0; t < 4; ++t) inv[t] = 1.0f / l_run[t];

  const int b = bh >> 4, nh = bh & 15;
  #pragma unroll
  for (int j2 = 0; j2 < 8; ++j2)
    #pragma unroll
    for (int rr = 0; rr < 4; ++rr) {
      const int row = qrow0 + (q << 2) + rr;
      ctx[((long)(b * S + row) * NH + nh) * HD + (j2 << 4) + r] = f2bf(o[j2][rr] * inv[rr]);
    }
}

// ---------------- external-memory attention (one wave per token) ----------------
__global__ __launch_bounds__(256) void k_ext_attn(const float* __restrict__ attn,
                                                  const float* __restrict__ ek,
                                                  const float* __restrict__ ev,
                                                  bf16* __restrict__ ectx) {
  const int wave = threadIdx.x >> 6, lane = threadIdx.x & 63;
  const long t = (long)blockIdx.x * 4 + wave;  // (b*NH + nh)*S + s
  const int b = (int)(t >> 15);
  const int nh = (int)((t >> 11) & 15);
  const int s = (int)(t & 2047);

  const float2 q2 = *(const float2*)(attn + (long)(b * S + s) * H + nh * HD + (lane << 1));
  const float* kp = ek + t * (KE * HD);
  const float* vp = ev + t * (KE * HD);

  constexpr float kscale = 0.08838834764831845f * 1.4426950408889634f;
  float sc[KE];
  #pragma unroll
  for (int k = 0; k < KE; ++k) {
    float2 kk = *(const float2*)(kp + k * HD + (lane << 1));
    float d = q2.x * kk.x + q2.y * kk.y;
    #pragma unroll
    for (int mk = 1; mk < 64; mk <<= 1) d += __shfl_xor(d, mk);
    sc[k] = d * kscale;
  }
  float mx = sc[0];
  #pragma unroll
  for (int k = 1; k < KE; ++k) mx = fmaxf(mx, sc[k]);
  float wk[KE], sum = 0.f;
  #pragma unroll
  for (int k = 0; k < KE; ++k) { wk[k] = exp2f(sc[k] - mx); sum += wk[k]; }
  const float inv = 1.f / sum;
  float ox = 0.f, oy = 0.f;
  #pragma unroll
  for (int k = 0; k < KE; ++k) {
    float2 vv = *(const float2*)(vp + k * HD + (lane << 1));
    ox += wk[k] * vv.x; oy += wk[k] * vv.y;
  }
  bf16x2 o2 = { f2bf(ox * inv), f2bf(oy * inv) };
  *(bf16x2*)&ectx[((long)(b * S + s) * NH + nh) * HD + (lane << 1)] = o2;
}

// ---------------- host orchestration ----------------
extern "C" void kernel_launch(void* const* d_in, const int* in_sizes, int n_in,
                              void* d_out, int out_size, void* d_ws, size_t ws_size,
                              hipStream_t stream) {
  const float* hs    = (const float*)d_in[0];
  const float* ext_k = (const float*)d_in[1];
  const float* ext_v = (const float*)d_in[2];
  const float* Wq    = (const float*)d_in[3];
  const float* Wk    = (const float*)d_in[4];
  const float* Wv    = (const float*)d_in[5];
  const float* Wo    = (const float*)d_in[6];
  const float* We    = (const float*)d_in[7];
  const float* Wg    = (const float*)d_in[8];
  const float* bg    = (const float*)d_in[9];
  float* out = (float*)d_out;

  char* ws = (char*)d_ws;
  bf16* hs_bf = (bf16*)ws;                       // 32 MB, reused as ctx
  bf16* Wt    = (bf16*)(ws + 33554432);          //  8 MB (per-GEMM transposed weight)
  bf16* qb    = (bf16*)(ws + 41943040);          // 32 MB, reused as ectx
  bf16* kb    = (bf16*)(ws + 75497472);          // 32 MB
  bf16* vtb   = (bf16*)(ws + 109051904);         // 32 MB
  float* g    = (float*)(ws + 142606336);        // 64 KB
  bf16* ctx   = hs_bf;
  bf16* ectx  = qb;
  float* attn = out;                             // d_out doubles as attn_output buffer

  dim3 blk(256);
  dim3 tgrid(H / 32, H / 32);
  dim3 ggrid(H / 128, M / 128);

  k_conv_bf16<<<dim3((M * H / 4 + 255) / 256), blk, 0, stream>>>(hs, hs_bf, M * H / 4);
  k_gate<<<dim3(M / 4), blk, 0, stream>>>(hs, Wg, bg, g);

  k_transpose_w<<<tgrid, blk, 0, stream>>>(Wq, Wt);
  k_gemm<0><<<ggrid, blk, 0, stream>>>(hs_bf, Wt, qb, nullptr, nullptr);
  k_transpose_w<<<tgrid, blk, 0, stream>>>(Wk, Wt);
  k_gemm<0><<<ggrid, blk, 0, stream>>>(hs_bf, Wt, kb, nullptr, nullptr);
  k_transpose_w<<<tgrid, blk, 0, stream>>>(Wv, Wt);
  k_gemm<3><<<ggrid, blk, 0, stream>>>(hs_bf, Wt, vtb, nullptr, nullptr);

  k_flash<<<dim3(S / 64, B * NH), blk, 0, stream>>>(qb, kb, vtb, ctx);

  k_transpose_w<<<tgrid, blk, 0, stream>>>(Wo, Wt);
  k_gemm<1><<<ggrid, blk, 0, stream>>>(ctx, Wt, attn, nullptr, nullptr);

  k_ext_attn<<<dim3(B * NH * S / 4), blk, 0, stream>>>(attn, ext_k, ext_v, ectx);

  k_transpose_w<<<tgrid, blk, 0, stream>>>(We, Wt);
  k_gemm<2><<<ggrid, blk, 0, stream>>>(ectx, Wt, out, attn, g);
}